// Round 16
// baseline (140.869 us; speedup 1.0000x reference)
//
#include <hip/hip_runtime.h>
#include <hip/hip_bf16.h>

#define NUM_RATINGS 10
#define WIN 1024
#define MAXT 74   // max padded tiles/window: 1024/16 + 10 pad-tails

typedef short bf16x8 __attribute__((ext_vector_type(8)));
typedef float f32x4 __attribute__((ext_vector_type(4)));

// ---- RNE f32 -> bf16 packing (static indexing only) ----
static __device__ __forceinline__ bf16x8 rne8(float4 a, float4 b) {
    float f[8] = {a.x, a.y, a.z, a.w, b.x, b.y, b.z, b.w};
    union { unsigned short us[8]; bf16x8 v; } U;
    #pragma unroll
    for (int i = 0; i < 8; ++i) {
        unsigned u = __float_as_uint(f[i]);
        U.us[i] = (unsigned short)((u + 0x7fffu + ((u >> 16) & 1u)) >> 16);
    }
    return U.v;
}

static __device__ __forceinline__ bf16x8 rne8s(float4 a, float4 b, float s) {
    float f[8] = {a.x, a.y, a.z, a.w, b.x, b.y, b.z, b.w};
    union { unsigned short us[8]; bf16x8 v; } U;
    #pragma unroll
    for (int i = 0; i < 8; ++i) {
        unsigned u = __float_as_uint(f[i] * s);
        U.us[i] = (unsigned short)((u + 0x7fffu + ((u >> 16) & 1u)) >> 16);
    }
    return U.v;
}

// ---------------- W -> bf16 fragment precompute (verified round 6) ---------
// wf[(r*8 + j)*64 + lane], j = tt*2 + ks.
// Lane l (eh=l&15, kg=l>>4) holds W[r][16*tt + eh][32*ks + 8*kg + i], i=0..7.
__global__ void k_wfrag(const float* __restrict__ w, bf16x8* __restrict__ wf) {
    int r = blockIdx.x;
    int lane = threadIdx.x & 63;
    int eh = lane & 15, kg = lane >> 4;
    #pragma unroll
    for (int j = 0; j < 8; ++j) {
        int tt = j >> 1, ks = j & 1;
        const float4* p = reinterpret_cast<const float4*>(
            w + ((size_t)r << 12) + (size_t)(16 * tt + eh) * 64 + 32 * ks + 8 * kg);
        wf[(r * 8 + j) * 64 + lane] = rne8(p[0], p[1]);
    }
}

// ---------------- windowed local-sort main ----------------
// One block = one 1024-edge window. Phase 1: LDS counting sort by rating
// (padded buckets, pads nd=-1). Phase 2: rating-uniform 16-edge tiles.
// SWAPPED MFMA (W-frag as M-side, x-frag as N-side): D col = lane's own edge
// (eh), D row = out-dim => acc[tt] = 4 consecutive outs 16tt+4kg..+3 of edge
// eh. Store = 4 dwordx4/tile (16 full lines each), no shfl, per-lane pad
// predication. Cuts vmem instructions/tile 20 -> 8 (TA-throughput fix).
__global__ __launch_bounds__(256) void k_main(
    const float* __restrict__ embed, const bf16x8* __restrict__ wf,
    const float* __restrict__ invc, const int* __restrict__ enode,
    const int* __restrict__ erating, float* __restrict__ out, int E) {

    __shared__ int2 smeta[MAXT * 16];          // 9472 B
    __shared__ int shist[NUM_RATINGS];
    __shared__ int spoff[NUM_RATINGS + 1];

    int tid = threadIdx.x;
    int base = blockIdx.x * WIN;

    if (tid < NUM_RATINGS) shist[tid] = 0;
    for (int i = tid; i < MAXT * 16; i += 256) smeta[i] = make_int2(-1, 0);
    __syncthreads();

    // histogram (4 edges/thread, coalesced); kk = unique index within bucket
    int er[4], rr[4], kk[4];
    #pragma unroll
    for (int i = 0; i < 4; ++i) {
        int e = base + i * 256 + tid;
        er[i] = e;
        if (e < E) {
            rr[i] = erating[e];
            kk[i] = atomicAdd(&shist[rr[i]], 1);
        }
    }
    __syncthreads();
    if (tid == 0) {
        int s = 0;
        #pragma unroll
        for (int r = 0; r < NUM_RATINGS; ++r) { spoff[r] = s; s += (shist[r] + 15) & ~15; }
        spoff[NUM_RATINGS] = s;
    }
    __syncthreads();
    // scatter into padded rating-sorted LDS slots
    #pragma unroll
    for (int i = 0; i < 4; ++i)
        if (er[i] < E)
            smeta[spoff[rr[i]] + kk[i]] =
                make_int2(enode[er[i]], __float_as_int(invc[er[i]]));
    __syncthreads();

    // uniform scalar copies
    int pf1 = spoff[1], pf2 = spoff[2], pf3 = spoff[3], pf4 = spoff[4];
    int pf5 = spoff[5], pf6 = spoff[6], pf7 = spoff[7], pf8 = spoff[8];
    int pf9 = spoff[9];
    int Tp = spoff[NUM_RATINGS] >> 4;

    int lane = tid & 63, wv = tid >> 6;
    int eh = lane & 15, kg = lane >> 4;

    int tpw = (Tp + 3) >> 2;
    int t0 = wv * tpw;
    int t1 = t0 + tpw; if (t1 > Tp) t1 = Tp;
    if (t0 >= t1) return;   // no barriers after this point

    // pipeline prologue: tile t0 meta + x
    int2 mc = smeta[(t0 << 4) + eh];
    const float4* xp0 = reinterpret_cast<const float4*>(
        embed + ((size_t)(mc.x < 0 ? 0 : mc.x) << 6));
    float4 xc0 = xp0[2 * kg], xc1 = xp0[2 * kg + 1];
    float4 xc2 = xp0[8 + 2 * kg], xc3 = xp0[9 + 2 * kg];

    int cur_r = -1;
    bf16x8 B[8];

    for (int t = t0; t < t1; ++t) {
        // prefetch next tile's meta + x (window-local gather)
        int tn = (t + 1 < t1) ? t + 1 : t;
        int2 mn = smeta[(tn << 4) + eh];
        const float4* xq = reinterpret_cast<const float4*>(
            embed + ((size_t)(mn.x < 0 ? 0 : mn.x) << 6));
        float4 xn0 = xq[2 * kg], xn1 = xq[2 * kg + 1];
        float4 xn2 = xq[8 + 2 * kg], xn3 = xq[9 + 2 * kg];

        // rating of tile t (uniform select chain; buckets are tile-aligned)
        int tslot = t << 4;
        int r = 0;
        r += tslot >= pf1; r += tslot >= pf2; r += tslot >= pf3;
        r += tslot >= pf4; r += tslot >= pf5; r += tslot >= pf6;
        r += tslot >= pf7; r += tslot >= pf8; r += tslot >= pf9;
        if (r != cur_r) {
            cur_r = r;
            #pragma unroll
            for (int j = 0; j < 8; ++j) B[j] = wf[(r * 8 + j) * 64 + lane];
        }

        float s_ = mc.x < 0 ? 0.f : __int_as_float(mc.y);
        bf16x8 a0 = rne8s(xc0, xc1, s_);   // k = 8kg..8kg+7
        bf16x8 a1 = rne8s(xc2, xc3, s_);   // k = 32+8kg..+7

        // SWAPPED operand order: W-frag = M-side, x-frag = N-side.
        // acc[tt][rg] = h[edge eh][out 16tt + 4kg + rg] (scale folded via x).
        f32x4 acc[4];
        #pragma unroll
        for (int tt = 0; tt < 4; ++tt) acc[tt] = (f32x4){0.f, 0.f, 0.f, 0.f};
        #pragma unroll
        for (int tt = 0; tt < 4; ++tt) {
            acc[tt] = __builtin_amdgcn_mfma_f32_16x16x32_bf16(B[2 * tt],     a0, acc[tt], 0, 0, 0);
            acc[tt] = __builtin_amdgcn_mfma_f32_16x16x32_bf16(B[2 * tt + 1], a1, acc[tt], 0, 0, 0);
        }

        // store: lane owns edge eh's outs [16tt+4kg .. +3] -> 4x dwordx4
        if (mc.x >= 0) {
            float* po = out + ((size_t)mc.x << 6) + (kg << 2);
            #pragma unroll
            for (int tt = 0; tt < 4; ++tt)
                __builtin_nontemporal_store(acc[tt], reinterpret_cast<f32x4*>(po + 16 * tt));
        }

        mc = mn;
        xc0 = xn0; xc1 = xn1; xc2 = xn2; xc3 = xn3;
    }
}

extern "C" void kernel_launch(void* const* d_in, const int* in_sizes, int n_in,
                              void* d_out, int out_size, void* d_ws, size_t ws_size,
                              hipStream_t stream) {
    const float* embed   = (const float*)d_in[0];
    const float* weights = (const float*)d_in[1];
    const float* invc    = (const float*)d_in[2];
    const int*   enode   = (const int*)d_in[3];
    const int*   erating = (const int*)d_in[4];
    float* out = (float*)d_out;

    int E = in_sizes[3];

    bf16x8* wf = (bf16x8*)d_ws;   // 80 KiB W fragments (L2-hot)

    hipLaunchKernelGGL(k_wfrag, dim3(NUM_RATINGS), dim3(64), 0, stream, weights, wf);

    int nW = (E + WIN - 1) / WIN;
    hipLaunchKernelGGL(k_main, dim3(nW), dim3(256), 0, stream,
                       embed, wf, invc, enode, erating, out, E);
}

// Round 17
// 131.316 us; speedup vs baseline: 1.0727x; 1.0727x over previous
//
#include <hip/hip_runtime.h>
#include <hip/hip_bf16.h>

#define NUM_RATINGS 10
#define WIN 1024
#define MAXT 74   // max padded tiles/window: 1024/16 + 10 pad-tails

typedef short bf16x8 __attribute__((ext_vector_type(8)));
typedef float f32x4 __attribute__((ext_vector_type(4)));

// ---- RNE f32 -> bf16 packing (static indexing only) ----
static __device__ __forceinline__ bf16x8 rne8(float4 a, float4 b) {
    float f[8] = {a.x, a.y, a.z, a.w, b.x, b.y, b.z, b.w};
    union { unsigned short us[8]; bf16x8 v; } U;
    #pragma unroll
    for (int i = 0; i < 8; ++i) {
        unsigned u = __float_as_uint(f[i]);
        U.us[i] = (unsigned short)((u + 0x7fffu + ((u >> 16) & 1u)) >> 16);
    }
    return U.v;
}

static __device__ __forceinline__ bf16x8 rne8s(float4 a, float4 b, float s) {
    float f[8] = {a.x, a.y, a.z, a.w, b.x, b.y, b.z, b.w};
    union { unsigned short us[8]; bf16x8 v; } U;
    #pragma unroll
    for (int i = 0; i < 8; ++i) {
        unsigned u = __float_as_uint(f[i] * s);
        U.us[i] = (unsigned short)((u + 0x7fffu + ((u >> 16) & 1u)) >> 16);
    }
    return U.v;
}

// ---------------- W -> bf16 fragment precompute (verified round 6) ---------
// wf[(r*8 + j)*64 + lane], j = tt*2 + ks.
// Lane l (eh=l&15, kg=l>>4) holds W[r][16*tt + eh][32*ks + 8*kg + i], i=0..7.
__global__ void k_wfrag(const float* __restrict__ w, bf16x8* __restrict__ wf) {
    int r = blockIdx.x;
    int lane = threadIdx.x & 63;
    int eh = lane & 15, kg = lane >> 4;
    #pragma unroll
    for (int j = 0; j < 8; ++j) {
        int tt = j >> 1, ks = j & 1;
        const float4* p = reinterpret_cast<const float4*>(
            w + ((size_t)r << 12) + (size_t)(16 * tt + eh) * 64 + 32 * ks + 8 * kg);
        wf[(r * 8 + j) * 64 + lane] = rne8(p[0], p[1]);
    }
}

// ---------------- windowed local-sort main ----------------
// One block = one 1024-edge window. Phase 1: LDS counting sort by rating
// (padded buckets, pads nd=-1). Phase 2: rating-uniform 16-edge tiles.
// SWAPPED MFMA (W-frag as M-side, x-frag as N-side): D col = lane's own edge
// (eh), D row = out-dim => acc[tt] = outs 16tt+4kg..+3 of edge eh. Store =
// 4 dwordx4/tile, REGULAR stores (no nt): L2 write-combines the 64B pieces
// into full lines (r16's nt caused partial-line HBM writes, WRITE +29MB).
__global__ __launch_bounds__(256) void k_main(
    const float* __restrict__ embed, const bf16x8* __restrict__ wf,
    const float* __restrict__ invc, const int* __restrict__ enode,
    const int* __restrict__ erating, float* __restrict__ out, int E) {

    __shared__ int2 smeta[MAXT * 16];          // 9472 B
    __shared__ int shist[NUM_RATINGS];
    __shared__ int spoff[NUM_RATINGS + 1];

    int tid = threadIdx.x;
    int base = blockIdx.x * WIN;

    if (tid < NUM_RATINGS) shist[tid] = 0;
    for (int i = tid; i < MAXT * 16; i += 256) smeta[i] = make_int2(-1, 0);
    __syncthreads();

    // histogram (4 edges/thread, coalesced); kk = unique index within bucket
    int er[4], rr[4], kk[4];
    #pragma unroll
    for (int i = 0; i < 4; ++i) {
        int e = base + i * 256 + tid;
        er[i] = e;
        if (e < E) {
            rr[i] = erating[e];
            kk[i] = atomicAdd(&shist[rr[i]], 1);
        }
    }
    __syncthreads();
    if (tid == 0) {
        int s = 0;
        #pragma unroll
        for (int r = 0; r < NUM_RATINGS; ++r) { spoff[r] = s; s += (shist[r] + 15) & ~15; }
        spoff[NUM_RATINGS] = s;
    }
    __syncthreads();
    // scatter into padded rating-sorted LDS slots
    #pragma unroll
    for (int i = 0; i < 4; ++i)
        if (er[i] < E)
            smeta[spoff[rr[i]] + kk[i]] =
                make_int2(enode[er[i]], __float_as_int(invc[er[i]]));
    __syncthreads();

    // uniform scalar copies
    int pf1 = spoff[1], pf2 = spoff[2], pf3 = spoff[3], pf4 = spoff[4];
    int pf5 = spoff[5], pf6 = spoff[6], pf7 = spoff[7], pf8 = spoff[8];
    int pf9 = spoff[9];
    int Tp = spoff[NUM_RATINGS] >> 4;

    int lane = tid & 63, wv = tid >> 6;
    int eh = lane & 15, kg = lane >> 4;

    int tpw = (Tp + 3) >> 2;
    int t0 = wv * tpw;
    int t1 = t0 + tpw; if (t1 > Tp) t1 = Tp;
    if (t0 >= t1) return;   // no barriers after this point

    // pipeline prologue: tile t0 meta + x
    int2 mc = smeta[(t0 << 4) + eh];
    const float4* xp0 = reinterpret_cast<const float4*>(
        embed + ((size_t)(mc.x < 0 ? 0 : mc.x) << 6));
    float4 xc0 = xp0[2 * kg], xc1 = xp0[2 * kg + 1];
    float4 xc2 = xp0[8 + 2 * kg], xc3 = xp0[9 + 2 * kg];

    int cur_r = -1;
    bf16x8 B[8];

    for (int t = t0; t < t1; ++t) {
        // prefetch next tile's meta + x (window-local gather)
        int tn = (t + 1 < t1) ? t + 1 : t;
        int2 mn = smeta[(tn << 4) + eh];
        const float4* xq = reinterpret_cast<const float4*>(
            embed + ((size_t)(mn.x < 0 ? 0 : mn.x) << 6));
        float4 xn0 = xq[2 * kg], xn1 = xq[2 * kg + 1];
        float4 xn2 = xq[8 + 2 * kg], xn3 = xq[9 + 2 * kg];

        // rating of tile t (uniform select chain; buckets are tile-aligned)
        int tslot = t << 4;
        int r = 0;
        r += tslot >= pf1; r += tslot >= pf2; r += tslot >= pf3;
        r += tslot >= pf4; r += tslot >= pf5; r += tslot >= pf6;
        r += tslot >= pf7; r += tslot >= pf8; r += tslot >= pf9;
        if (r != cur_r) {
            cur_r = r;
            #pragma unroll
            for (int j = 0; j < 8; ++j) B[j] = wf[(r * 8 + j) * 64 + lane];
        }

        float s_ = mc.x < 0 ? 0.f : __int_as_float(mc.y);
        bf16x8 a0 = rne8s(xc0, xc1, s_);   // k = 8kg..8kg+7
        bf16x8 a1 = rne8s(xc2, xc3, s_);   // k = 32+8kg..+7

        // SWAPPED operand order: W-frag = M-side, x-frag = N-side.
        // acc[tt][rg] = h[edge eh][out 16tt + 4kg + rg] (scale folded via x).
        f32x4 acc[4];
        #pragma unroll
        for (int tt = 0; tt < 4; ++tt) acc[tt] = (f32x4){0.f, 0.f, 0.f, 0.f};
        #pragma unroll
        for (int tt = 0; tt < 4; ++tt) {
            acc[tt] = __builtin_amdgcn_mfma_f32_16x16x32_bf16(B[2 * tt],     a0, acc[tt], 0, 0, 0);
            acc[tt] = __builtin_amdgcn_mfma_f32_16x16x32_bf16(B[2 * tt + 1], a1, acc[tt], 0, 0, 0);
        }

        // store: lane owns edge eh's outs [16tt+4kg .. +3] -> 4x dwordx4,
        // regular stores so L2 assembles full 128B lines before HBM flush
        if (mc.x >= 0) {
            float* po = out + ((size_t)mc.x << 6) + (kg << 2);
            #pragma unroll
            for (int tt = 0; tt < 4; ++tt)
                *reinterpret_cast<f32x4*>(po + 16 * tt) = acc[tt];
        }

        mc = mn;
        xc0 = xn0; xc1 = xn1; xc2 = xn2; xc3 = xn3;
    }
}

extern "C" void kernel_launch(void* const* d_in, const int* in_sizes, int n_in,
                              void* d_out, int out_size, void* d_ws, size_t ws_size,
                              hipStream_t stream) {
    const float* embed   = (const float*)d_in[0];
    const float* weights = (const float*)d_in[1];
    const float* invc    = (const float*)d_in[2];
    const int*   enode   = (const int*)d_in[3];
    const int*   erating = (const int*)d_in[4];
    float* out = (float*)d_out;

    int E = in_sizes[3];

    bf16x8* wf = (bf16x8*)d_ws;   // 80 KiB W fragments (L2-hot)

    hipLaunchKernelGGL(k_wfrag, dim3(NUM_RATINGS), dim3(64), 0, stream, weights, wf);

    int nW = (E + WIN - 1) / WIN;
    hipLaunchKernelGGL(k_main, dim3(nW), dim3(256), 0, stream,
                       embed, wf, invc, enode, erating, out, E);
}